// Round 2
// baseline (379.324 us; speedup 1.0000x reference)
//
#include <hip/hip_runtime.h>
#include <hip/hip_bf16.h>

// SplineCNN block.
// Edge records (32 B, CSR(dst) order), word order:
//   w0=wx[0..3], w1=wx[4..7], w2=bas01, w3=bas23, w4=bas45, w5=bas67, w6=src, w7=0
// conv1/conv2 fused, 512 thr / 8 nodes, wave-per-node:
//   Phase 1 = MFMA scatter-GEMM with K-slot mapping kidx = j*4 + quad
//   (early-exit at jmax = ceil(cnt/4), conflict-free record reads).
//   s_waitcnt(0) between record staging writes and read-back (r15 flake).
//   S stored bf16 (pitch 904). Phase 2: MFMA GEMM, A = 28 ds_read_b128,
//   accS/accR split, invd scaling in epilogue.
// conv3: SAME fused S-scheme generalized to CIN=96 (replaces the old
//   Z = h3 @ Wp3 dense GEMM + shfl gather-aggregate, which cost 90 MB Z
//   write + ~195 MB random Z gather from HBM). Phase 1: 6 A-tiles x 2
//   B-tiles = 12 MFMA / 32-edge chunk, S row = 27*96 + 96 root (SP3=2696,
//   stride mod 16 == 8 keeps phase-2 ds_read at 4-way conflict).
//   Phase 2: K=2688 GEMM split 4-way over waves (21 K-tiles each), LDS
//   reduction; kq=3 waves own the root tiles + epilogue + final store.
// Scan: two-level parallel (196-block partial + top + add).

#define EPS 1e-5f
#define MAXN 50176
#define MAXE 401408
#define SP2 904    // bf16 elems per S row (conv1/2): 864 spline + 32 root + 8 pad
#define SP3 2696   // bf16 elems per S row (conv3): 2592 spline + 96 root + 8 pad

typedef __attribute__((ext_vector_type(8))) short short8;
typedef __attribute__((ext_vector_type(4))) float floatx4;

__device__ int             g_deg[MAXN];
__device__ int             g_offs[MAXN + 1];
__device__ int             g_cursor[MAXN];
__device__ int             g_bsum[256];
__device__ uint4           g_emeta[MAXE * 2];
__device__ __align__(16) __hip_bfloat16 g_h0[MAXN * 32];
__device__ __align__(16) __hip_bfloat16 g_h1[MAXN * 32];
__device__ __align__(16) __hip_bfloat16 g_h2[MAXN * 64];
__device__ __align__(16) __hip_bfloat16 g_h3[MAXN * 96];
__device__ __align__(16) __hip_bfloat16 g_Wp1[28672];
__device__ __align__(16) __hip_bfloat16 g_Wp2[57344];
__device__ __align__(16) __hip_bfloat16 g_Wp3[86016];
__device__ float           g_stats[128];
__device__ int             g_isbf16;

__device__ __forceinline__ float loadf(const void* p, int i, bool bf)
{
    return bf ? (float)((const __hip_bfloat16*)p)[i] : ((const float*)p)[i];
}
__device__ __forceinline__ float bf16f(unsigned int u)
{
    return __uint_as_float(u << 16);
}
__device__ __forceinline__ unsigned short bfbits(float f)
{
    union { __hip_bfloat16 h; unsigned short u; } cv;
    cv.h = __float2bfloat16(f);
    return cv.u;
}

// ---------------- K1: zero-init scratch + wire dtype detect ----------------
__global__ void init_detect(const unsigned int* __restrict__ x, int n)
{
    int i = blockIdx.x * blockDim.x + threadIdx.x;
    if (blockIdx.x == 0 && threadIdx.x < 64) {
        int lane = threadIdx.x;
        int cnt = 0;
        for (int k = lane; k < 256; k += 64) {
            unsigned int lo = x[k] & 0xFFFFu;
            int ex = (int)((lo >> 7) & 0xFFu);
            if (lo == 0u || (ex >= 96 && ex <= 140)) cnt++;
        }
#pragma unroll
        for (int o = 1; o < 64; o <<= 1) cnt += __shfl_xor(cnt, o, 64);
        if (lane == 0) g_isbf16 = (cnt >= 200) ? 1 : 0;
    }
    if (i < n) { g_deg[i] = 0; g_cursor[i] = 0; }
    if (i < 128) g_stats[i] = 0.0f;
}

// ---------------- weight pack helpers (device) ----------------
template <int COUT>
__device__ __forceinline__ void prep_ws_dev(const void* W, const void* root,
                                            __hip_bfloat16* Wp, int t, bool bf)
{
    int j = t & 7;
    int lane = (t >> 3) & 63;
    int rest = t >> 9;
    int kk = rest % 28;
    int nt = rest / 28;
    int k = kk * 32 + (lane >> 4) * 8 + j;
    int o = nt * 16 + (lane & 15);
    float v = (k < 864) ? loadf(W, k * COUT + o, bf)
                        : loadf(root, (k - 864) * COUT + o, bf);
    Wp[t] = __float2bfloat16(v);
}

// conv3 pack: K axis = bin*96 + ch (2592 spline) then 96 root channels.
// B-fragment layout matches phase-2 read: t = ((nt*84+kk)*64+lane)*8 + j,
// element k = kk*32 + quad*8 + j, col o = nt*16 + m. Channels 67..95 are 0
// (h3 pads 64 BN-ELU ch + 3 pos ch to 96).
__device__ __forceinline__ void prep_w3_dev(const void* W, const void* root,
                                            __hip_bfloat16* Wp, int t, bool bf)
{
    const int KB = 84;
    int j = t & 7;
    int lane = (t >> 3) & 63;
    int rest = t >> 9;          // < 168
    int kk = rest % KB;         // 0..83
    int nt = rest / KB;         // 0..1
    int k = kk * 32 + (lane >> 4) * 8 + j;   // 0..2687
    int o = nt * 16 + (lane & 15);           // 0..31
    float v = 0.0f;
    if (k < 2592) {
        int bin = k / 96;
        int ch = k - bin * 96;
        if (ch < 67) v = loadf(W, (bin * 67 + ch) * 32 + o, bf);
    } else {
        int ch = k - 2592;
        if (ch < 67) v = loadf(root, ch * 32 + o, bf);
    }
    Wp[t] = __float2bfloat16(v);
}

// ---------------- K2: degree count + cast x + pack all weights ----------------
__global__ void misc_kernel(const int* __restrict__ dst, const void* __restrict__ x,
                            const void* W1, const void* r1,
                            const void* W2, const void* r2,
                            const void* W3, const void* r3, int E, int N)
{
    int t = blockIdx.x * blockDim.x + threadIdx.x;
    const bool bf = (g_isbf16 != 0);
    if (t < E) { atomicAdd(&g_deg[dst[t]], 1); return; }
    t -= E;
    int nx = N * 32;
    if (t < nx) { g_h0[t] = __float2bfloat16(loadf(x, t, bf)); return; }
    t -= nx;
    if (t < 28672) { prep_ws_dev<32>(W1, r1, g_Wp1, t, bf); return; }
    t -= 28672;
    if (t < 57344) { prep_ws_dev<64>(W2, r2, g_Wp2, t, bf); return; }
    t -= 57344;
    if (t < 86016) { prep_w3_dev(W3, r3, g_Wp3, t, bf); return; }
}

// ---------------- K3a: per-block scan (256 elems/block) ----------------
__global__ void scan_blk(int n)
{
    __shared__ int buf[256];
    int tid = threadIdx.x;
    int i = blockIdx.x * 256 + tid;
    int v = (i < n) ? g_deg[i] : 0;
    buf[tid] = v;
    __syncthreads();
    for (int o = 1; o < 256; o <<= 1) {
        int t = (tid >= o) ? buf[tid - o] : 0;
        __syncthreads();
        buf[tid] += t;
        __syncthreads();
    }
    if (i < n) g_offs[i] = buf[tid] - v;   // block-local exclusive
    if (tid == 255) g_bsum[blockIdx.x] = buf[255];
}

// ---------------- K3b: scan of block sums (1 block; nb <= 256) ----------------
__global__ void scan_top(int nb, int n)
{
    __shared__ int buf[256];
    int tid = threadIdx.x;
    int v = (tid < nb) ? g_bsum[tid] : 0;
    buf[tid] = v;
    __syncthreads();
    for (int o = 1; o < 256; o <<= 1) {
        int t = (tid >= o) ? buf[tid - o] : 0;
        __syncthreads();
        buf[tid] += t;
        __syncthreads();
    }
    if (tid < nb) g_bsum[tid] = buf[tid] - v;   // exclusive
    if (tid == nb - 1) g_offs[n] = buf[tid];    // total = E
}

// ---------------- K3c: add block offsets ----------------
__global__ void scan_add(int n)
{
    int i = blockIdx.x * 256 + threadIdx.x;
    if (i < n) g_offs[i] += g_bsum[i >> 8];
}

// ---------------- K4: basis + CSR fill (32-B edge records) ----------------
__global__ void basis_fill(const void* __restrict__ attr,
                           const int* __restrict__ src,
                           const int* __restrict__ dst, int E)
{
    int e = blockIdx.x * blockDim.x + threadIdx.x;
    if (e >= E) return;
    const bool bf = (g_isbf16 != 0);
    float f[3];
    int lo[3];
#pragma unroll
    for (int d = 0; d < 3; ++d) {
        float a = loadf(attr, e * 3 + d, bf);
        float s = a * 3.0f;
        float l = floorf(s);
        lo[d] = (int)l;
        f[d] = s - l;
    }
    const int p3[3] = {1, 3, 9};
    unsigned int wxp0 = 0, wxp1 = 0;
    unsigned short bb[8];
#pragma unroll
    for (int b = 0; b < 8; ++b) {
        float w = 1.0f;
        int id = 0;
#pragma unroll
        for (int d = 0; d < 3; ++d) {
            int bit = (b >> d) & 1;
            w *= bit ? f[d] : (1.0f - f[d]);
            id += ((lo[d] + bit) % 3) * p3[d];
        }
        if (b < 4) wxp0 |= (unsigned int)id << (8 * b);
        else       wxp1 |= (unsigned int)id << (8 * (b - 4));
        bb[b] = bfbits(w);
    }
    int d = dst[e];
    int p = atomicAdd(&g_cursor[d], 1);
    int slot = g_offs[d] + p;
    g_emeta[slot * 2] = make_uint4(wxp0, wxp1,
                                   (unsigned int)bb[0] | ((unsigned int)bb[1] << 16),
                                   (unsigned int)bb[2] | ((unsigned int)bb[3] << 16));
    g_emeta[slot * 2 + 1] = make_uint4(
        (unsigned int)bb[4] | ((unsigned int)bb[5] << 16),
        (unsigned int)bb[6] | ((unsigned int)bb[7] << 16),
        (unsigned int)src[e], 0u);
}

// ---------------- fused conv (CIN=32), 8 nodes / 512 thr ----------------
// IN_SEL: 0 = g_h0, 1 = g_h1.  OUT_SEL: 1 = g_h1 (+ELU), 2 = g_h2 (raw).
template <int COUT, bool ELU, int IN_SEL, int OUT_SEL>
__global__ __launch_bounds__(512, 8) void fused_conv(const void* __restrict__ bias,
                                                     int N)
{
    __shared__ unsigned short Sb[8 * SP2];
    __shared__ uint4 recs[8][64];
    __shared__ float invd[8];
    int tid = threadIdx.x, wid = tid >> 6, lane = tid & 63;
    int nbase = blockIdx.x * 8;
    const bool bf = (g_isbf16 != 0);
    const unsigned short* xptr = (IN_SEL == 0) ? (const unsigned short*)g_h0
                                               : (const unsigned short*)g_h1;
    const __hip_bfloat16* Wp = (COUT == 32) ? g_Wp1 : g_Wp2;

    int n = nbase + wid;
    int m = lane & 15, quad = lane >> 4;

    // ---- phase 1: wave wid builds S row for its node via MFMA scatter-GEMM ----
    if (n < N) {
        int e0 = g_offs[n], e1 = g_offs[n + 1];
        floatx4 C00 = {}, C01 = {}, C10 = {}, C11 = {};
        uint4* myrec = &recs[wid][0];
        int bin0 = m, bin1 = m + 16;
        for (int base = e0; base < e1; base += 32) {
            int cnt = e1 - base; if (cnt > 32) cnt = 32;
            if (lane < 32) {
                uint4 v0 = make_uint4(0, 0, 0, 0), v1 = make_uint4(0, 0, 0, 0);
                if (lane < cnt) {
                    size_t le = (size_t)(base + lane) * 2;
                    v0 = g_emeta[le];
                    v1 = g_emeta[le + 1];
                }
                myrec[2 * lane] = v0;
                myrec[2 * lane + 1] = v1;
            }
            // drain this wave's outstanding DS writes before the read-back:
            // intra-wave write->read ordering is NOT assumed (r15 flaked).
            __builtin_amdgcn_s_waitcnt(0);
            int jmax = (cnt + 3) >> 2;   // wave-uniform; K-slots >= cnt are zeros
            unsigned a0w[4] = {0, 0, 0, 0}, a1w[4] = {0, 0, 0, 0};
            unsigned b0w[4] = {0, 0, 0, 0}, b1w[4] = {0, 0, 0, 0};
#pragma unroll
            for (int j = 0; j < 8; ++j) {
                if (j >= jmax) break;
                // K-permutation: fragment slot (quad, j) holds edge j*4+quad.
                int kidx = j * 4 + quad;
                uint4 ra = myrec[2 * kidx];                       // wx03,wx47,bas01,bas23
                uint2 rb = *(const uint2*)&myrec[2 * kidx + 1];   // bas45,bas67
                int sn = (int)((const unsigned*)&myrec[2 * kidx + 1])[2];
                unsigned av0 = xptr[(size_t)sn * 32 + m];
                unsigned av1 = xptr[(size_t)sn * 32 + 16 + m];
                unsigned p0 = 0, p1 = 0;
#pragma unroll
                for (int b = 0; b < 8; ++b) {
                    unsigned wx = ((b < 4 ? ra.x : ra.y) >> (8 * (b & 3))) & 0xFFu;
                    unsigned basw = (b < 2) ? ra.z : (b < 4) ? ra.w
                                  : (b < 6) ? rb.x : rb.y;
                    unsigned bas = (b & 1) ? (basw >> 16) : (basw & 0xFFFFu);
                    if (wx == (unsigned)bin0) p0 = bas;
                    if (wx == (unsigned)bin1) p1 = bas;
                }
                unsigned sh = 16 * (j & 1);
                a0w[j >> 1] |= av0 << sh;
                a1w[j >> 1] |= av1 << sh;
                b0w[j >> 1] |= p0 << sh;
                b1w[j >> 1] |= p1 << sh;
            }
            union U { unsigned w[4]; short8 v; } A0, A1, B0, B1;
#pragma unroll
            for (int q = 0; q < 4; ++q) {
                A0.w[q] = a0w[q]; A1.w[q] = a1w[q];
                B0.w[q] = b0w[q]; B1.w[q] = b1w[q];
            }
            C00 = __builtin_amdgcn_mfma_f32_16x16x32_bf16(A0.v, B0.v, C00, 0, 0, 0);
            C01 = __builtin_amdgcn_mfma_f32_16x16x32_bf16(A0.v, B1.v, C01, 0, 0, 0);
            C10 = __builtin_amdgcn_mfma_f32_16x16x32_bf16(A1.v, B0.v, C10, 0, 0, 0);
            C11 = __builtin_amdgcn_mfma_f32_16x16x32_bf16(A1.v, B1.v, C11, 0, 0, 0);
        }
        // writeback: C[mt][nt] lane holds col=m (bin-in-tile), rows quad*4+r (ch)
        unsigned short* Srow = Sb + wid * SP2;
        {
            floatx4 Cf[4] = {C00, C01, C10, C11};
#pragma unroll
            for (int f = 0; f < 4; ++f) {
                int mt = f >> 1, nt = f & 1;
                int bin = nt * 16 + m;
                if (bin < 27) {
                    union { unsigned short h[4]; uint2 u; } pk;
#pragma unroll
                    for (int r = 0; r < 4; ++r) pk.h[r] = bfbits(Cf[f][r]);
                    *(uint2*)(Srow + bin * 32 + mt * 16 + quad * 4) = pk.u;
                }
            }
        }
        if (lane < 32) Srow[864 + lane] = xptr[(size_t)n * 32 + lane];
        if (lane == 0) {
            int deg = e1 - e0;
            invd[wid] = 1.0f / (float)(deg < 1 ? 1 : deg);
        }
    }
    __syncthreads();

    // ---- phase 2: wave w = col-tile w of GEMM 16 x 896 @ 896 x COUT ----
    if (wid * 16 < COUT) {
        int mrow = m & 7;   // 8 nodes; rows 8..15 duplicate (discarded below)
        const unsigned short* Ab = Sb + mrow * SP2 + quad * 8;
        floatx4 accS = {}, accR = {};
#pragma unroll
        for (int kk = 0; kk < 28; ++kk) {
            short8 a = *(const short8*)(Ab + kk * 32);
            const short* bp = (const short*)Wp +
                ((size_t)(wid * 28 + kk) * 64 + lane) * 8;
            short8 b = *(const short8*)bp;
            if (kk < 27) accS = __builtin_amdgcn_mfma_f32_16x16x32_bf16(a, b, accS, 0, 0, 0);
            else         accR = __builtin_amdgcn_mfma_f32_16x16x32_bf16(a, b, accR, 0, 0, 0);
        }
        int o = wid * 16 + m;
        float bval = loadf(bias, o, bf);
#pragma unroll
        for (int r = 0; r < 4; ++r) {
            int slot = quad * 4 + r;
            if (slot >= 8) continue;
            int nn = nbase + slot;
            if (nn >= N) continue;
            float v = accS[r] * invd[slot] + accR[r] + bval;
            if (ELU) v = v > 0.0f ? v : expm1f(v);
            if (OUT_SEL == 1) g_h1[nn * 32 + o] = __float2bfloat16(v);
            else              g_h2[nn * 64 + o] = __float2bfloat16(v);
        }
    }
}

// ---------------- fused conv3 (CIN=96 from g_h3, COUT=32 to out) ----------------
// Same scatter-GEMM scheme as fused_conv, widened to 6 A-tiles. Phase 2 is a
// 16 x 2688 @ 2688 x 32 GEMM; K split 4-way across waves (21 K-tiles each),
// partials reduced through LDS; kq==3 waves hold the root tiles (kk 81..83,
// never invd-scaled) and run the epilogue + final store.
__global__ __launch_bounds__(512, 4) void fused_conv3(const void* __restrict__ bias,
                                                      void* __restrict__ out_ext,
                                                      int N)
{
    __shared__ __align__(16) unsigned short Sb[8 * SP3];   // 43136 B
    __shared__ union {
        uint4 recs[8][64];        // phase 1 edge records (8 KB)
        float red[6][64][4];      // phase 2 partial accS (6 KB)
    } u;
    __shared__ float invd[8];
    int tid = threadIdx.x, wid = tid >> 6, lane = tid & 63;
    int nbase = blockIdx.x * 8;
    const bool bf = (g_isbf16 != 0);
    const unsigned short* xptr = (const unsigned short*)g_h3;

    int n = nbase + wid;
    int m = lane & 15, quad = lane >> 4;

    // ---- phase 1: wave wid builds S row (27 bins x 96 ch) via MFMA scatter ----
    if (n < N) {
        int e0 = g_offs[n], e1 = g_offs[n + 1];
        floatx4 C[6][2];
#pragma unroll
        for (int t = 0; t < 6; ++t) {
            C[t][0] = (floatx4){0.f, 0.f, 0.f, 0.f};
            C[t][1] = (floatx4){0.f, 0.f, 0.f, 0.f};
        }
        uint4* myrec = &u.recs[wid][0];
        int bin0 = m, bin1 = m + 16;
        for (int base = e0; base < e1; base += 32) {
            int cnt = e1 - base; if (cnt > 32) cnt = 32;
            if (lane < 32) {
                uint4 v0 = make_uint4(0, 0, 0, 0), v1 = make_uint4(0, 0, 0, 0);
                if (lane < cnt) {
                    size_t le = (size_t)(base + lane) * 2;
                    v0 = g_emeta[le];
                    v1 = g_emeta[le + 1];
                }
                myrec[2 * lane] = v0;
                myrec[2 * lane + 1] = v1;
            }
            __builtin_amdgcn_s_waitcnt(0);   // r15: drain DS writes before read-back
            int jmax = (cnt + 3) >> 2;
            unsigned aw[6][4] = {{0, 0, 0, 0}, {0, 0, 0, 0}, {0, 0, 0, 0},
                                 {0, 0, 0, 0}, {0, 0, 0, 0}, {0, 0, 0, 0}};
            unsigned b0w[4] = {0, 0, 0, 0}, b1w[4] = {0, 0, 0, 0};
#pragma unroll
            for (int j = 0; j < 8; ++j) {
                if (j >= jmax) break;
                int kidx = j * 4 + quad;
                uint4 ra = myrec[2 * kidx];
                uint2 rb = *(const uint2*)&myrec[2 * kidx + 1];
                int sn = (int)((const unsigned*)&myrec[2 * kidx + 1])[2];
                const unsigned short* hr = xptr + (size_t)sn * 96 + m;
                unsigned av[6];
#pragma unroll
                for (int t = 0; t < 6; ++t) av[t] = hr[t * 16];
                unsigned p0 = 0, p1 = 0;
#pragma unroll
                for (int b = 0; b < 8; ++b) {
                    unsigned wx = ((b < 4 ? ra.x : ra.y) >> (8 * (b & 3))) & 0xFFu;
                    unsigned basw = (b < 2) ? ra.z : (b < 4) ? ra.w
                                  : (b < 6) ? rb.x : rb.y;
                    unsigned bas = (b & 1) ? (basw >> 16) : (basw & 0xFFFFu);
                    if (wx == (unsigned)bin0) p0 = bas;
                    if (wx == (unsigned)bin1) p1 = bas;
                }
                unsigned sh = 16 * (j & 1);
#pragma unroll
                for (int t = 0; t < 6; ++t) aw[t][j >> 1] |= av[t] << sh;
                b0w[j >> 1] |= p0 << sh;
                b1w[j >> 1] |= p1 << sh;
            }
            union U { unsigned w[4]; short8 v; } A, B0, B1;
#pragma unroll
            for (int q = 0; q < 4; ++q) { B0.w[q] = b0w[q]; B1.w[q] = b1w[q]; }
#pragma unroll
            for (int t = 0; t < 6; ++t) {
#pragma unroll
                for (int q = 0; q < 4; ++q) A.w[q] = aw[t][q];
                C[t][0] = __builtin_amdgcn_mfma_f32_16x16x32_bf16(A.v, B0.v, C[t][0], 0, 0, 0);
                C[t][1] = __builtin_amdgcn_mfma_f32_16x16x32_bf16(A.v, B1.v, C[t][1], 0, 0, 0);
            }
        }
        // writeback: C[t][nt] lane holds col=m (bin-in-tile), rows quad*4+r
        // (ch-in-tile) -> S[bin*96 + t*16 + quad*4 + r]
        unsigned short* Srow = Sb + wid * SP3;
#pragma unroll
        for (int t = 0; t < 6; ++t) {
#pragma unroll
            for (int ntile = 0; ntile < 2; ++ntile) {
                int bin = ntile * 16 + m;
                if (bin < 27) {
                    union { unsigned short h[4]; uint2 uu; } pk;
#pragma unroll
                    for (int r = 0; r < 4; ++r) pk.h[r] = bfbits(C[t][ntile][r]);
                    *(uint2*)(Srow + bin * 96 + t * 16 + quad * 4) = pk.uu;
                }
            }
        }
        for (int t2 = lane; t2 < 96; t2 += 64)
            Srow[2592 + t2] = xptr[(size_t)n * 96 + t2];
        if (lane == 0) {
            int deg = e1 - e0;
            invd[wid] = 1.0f / (float)(deg < 1 ? 1 : deg);
        }
    }
    __syncthreads();

    // ---- phase 2: GEMM 16 x 2688 @ 2688 x 32; wave = (col-tile nt, K-quarter kq)
    int nt = wid & 1, kq = wid >> 1;
    int mrow = m & 7;   // 8 nodes; rows 8..15 duplicate (discarded in epilogue)
    const unsigned short* Ab = Sb + mrow * SP3 + quad * 8;
    floatx4 accS = {}, accR = {};
    {
        int kbeg = kq * 21, kend = kbeg + 21;
        int ksplit = (kend < 81) ? kend : 81;   // root tiles are kk 81..83 (kq==3)
        for (int kk = kbeg; kk < ksplit; ++kk) {
            short8 a = *(const short8*)(Ab + kk * 32);
            const short* bp = (const short*)g_Wp3 +
                ((size_t)(nt * 84 + kk) * 64 + lane) * 8;
            short8 b = *(const short8*)bp;
            accS = __builtin_amdgcn_mfma_f32_16x16x32_bf16(a, b, accS, 0, 0, 0);
        }
        for (int kk = ksplit; kk < kend; ++kk) {
            short8 a = *(const short8*)(Ab + kk * 32);
            const short* bp = (const short*)g_Wp3 +
                ((size_t)(nt * 84 + kk) * 64 + lane) * 8;
            short8 b = *(const short8*)bp;
            accR = __builtin_amdgcn_mfma_f32_16x16x32_bf16(a, b, accR, 0, 0, 0);
        }
    }
    if (kq < 3)
        *(floatx4*)&u.red[wid][lane][0] = accS;
    __syncthreads();
    if (kq == 3) {
#pragma unroll
        for (int w = 0; w < 3; ++w)
            accS += *(const floatx4*)&u.red[2 * w + nt][lane][0];
        int o = nt * 16 + m;
        float bval = loadf(bias, o, bf);
#pragma unroll
        for (int r = 0; r < 4; ++r) {
            int slot = quad * 4 + r;
            if (slot >= 8) continue;
            int nn = nbase + slot;
            if (nn >= N) continue;
            float v = accS[r] * invd[slot] + accR[r] + bval;
            if (bf) ((__hip_bfloat16*)out_ext)[nn * 32 + o] = __float2bfloat16(v);
            else    ((float*)out_ext)[nn * 32 + o] = v;
        }
    }
}

// ---------------- BN stats (reads g_h2) ----------------
__global__ void bn_reduce(int n)
{
    int tid = threadIdx.x;
    int c = tid & 63;
    int r = tid >> 6;
    float s = 0.0f, s2 = 0.0f;
    for (int i = blockIdx.x * 4 + r; i < n; i += gridDim.x * 4) {
        float v = (float)g_h2[i * 64 + c];
        s += v; s2 += v * v;
    }
    __shared__ float b1s[256], b2s[256];
    b1s[tid] = s; b2s[tid] = s2;
    __syncthreads();
    if (r == 0) {
        s  = b1s[c] + b1s[c + 64] + b1s[c + 128] + b1s[c + 192];
        s2 = b2s[c] + b2s[c + 64] + b2s[c + 128] + b2s[c + 192];
        atomicAdd(&g_stats[c], s);
        atomicAdd(&g_stats[64 + c], s2);
    }
}

// ---------------- h3 = [elu(bn(h2)), pos, 0-pad] (96 ch), coef inline -------
__global__ void h3_build(const void* __restrict__ pos,
                         const void* __restrict__ gamma,
                         const void* __restrict__ beta, int N)
{
    __shared__ float cf[128];
    int t = threadIdx.x;
    const bool bf = (g_isbf16 != 0);
    if (t < 64) {
        float inv_n = 1.0f / (float)N;
        float mu = g_stats[t] * inv_n;
        float var = g_stats[64 + t] * inv_n - mu * mu;
        float A = rsqrtf(var + EPS) * loadf(gamma, t, bf);
        cf[t] = A;
        cf[64 + t] = loadf(beta, t, bf) - mu * A;
    }
    __syncthreads();
    int idx = blockIdx.x * blockDim.x + t;
    if (idx >= N * 96) return;
    int n = idx / 96, ch = idx - n * 96;
    float v;
    if (ch < 64) {
        float h = (float)g_h2[n * 64 + ch];
        v = h * cf[ch] + cf[64 + ch];
        v = v > 0.0f ? v : expm1f(v);
    } else if (ch < 67) {
        v = loadf(pos, n * 3 + (ch - 64), bf);
    } else {
        v = 0.0f;
    }
    g_h3[(size_t)n * 96 + ch] = __float2bfloat16(v);
}

extern "C" void kernel_launch(void* const* d_in, const int* in_sizes, int n_in,
                              void* d_out, int out_size, void* d_ws, size_t ws_size,
                              hipStream_t stream)
{
    const void* x      = d_in[0];
    const int*  eindex = (const int*)d_in[1];
    const void* eattr  = d_in[2];
    const void* pos    = d_in[3];
    const void* W1     = d_in[4];
    const void* root1  = d_in[5];
    const void* b1     = d_in[6];
    const void* W2     = d_in[7];
    const void* root2  = d_in[8];
    const void* b2     = d_in[9];
    const void* gamma  = d_in[10];
    const void* beta   = d_in[11];
    const void* W3     = d_in[12];
    const void* root3  = d_in[13];
    const void* b3     = d_in[14];
    (void)d_ws; (void)ws_size; (void)n_in; (void)out_size;

    const int N = in_sizes[0] / 32;
    const int E = in_sizes[1] / 2;
    const int* srcp = eindex;
    const int* dstp = eindex + E;

    init_detect<<<(N + 255) / 256, 256, 0, stream>>>((const unsigned int*)x, N);
    {
        int tot = E + N * 32 + 28672 + 57344 + 86016;
        misc_kernel<<<(tot + 255) / 256, 256, 0, stream>>>(
            dstp, x, W1, root1, W2, root2, W3, root3, E, N);
    }
    // two-level parallel scan
    int nb = (N + 255) / 256;   // 196 <= 256
    scan_blk<<<nb, 256, 0, stream>>>(N);
    scan_top<<<1, 256, 0, stream>>>(nb, N);
    scan_add<<<nb, 256, 0, stream>>>(N);
    basis_fill<<<(E + 255) / 256, 256, 0, stream>>>(eattr, srcp, dstp, E);

    int nb8 = (N + 7) / 8;
    fused_conv<32, true, 0, 1><<<nb8, 512, 0, stream>>>(b1, N);
    fused_conv<64, false, 1, 2><<<nb8, 512, 0, stream>>>(b2, N);
    bn_reduce<<<120, 256, 0, stream>>>(N);
    h3_build<<<(N * 96 + 255) / 256, 256, 0, stream>>>(pos, gamma, beta, N);
    fused_conv3<<<nb8, 512, 0, stream>>>(b3, d_out, N);
}